// Round 10
// baseline (147.471 us; speedup 1.0000x reference)
//
#include <hip/hip_runtime.h>
#include <hip/hip_bf16.h>

// AdaptiveGraphNetwork via MFMA 16x16x32 bf16. B=4096, N=64, D=32, H=64.
//
// v9 = v7 + REP=3 idempotent repeat loop -- INSTRUMENTATION BUILD.
// Purpose: the agn dispatch (~30us) has been invisible in rocprof top-5
// behind the harness's 42-45us poison fills since v3; five structural
// levers (v2 instr cut, v6 occupancy, v4 staging, v7 latency trims, v8
// zero-barrier) all landed 30-36us vs the 10.6us HBM floor, and the cycle
// model is off 4-5x -- the real bottleneck is unidentified. REP=3 makes the
// kernel ~90us -> top dispatch -> steady-state counters. Output is
// recomputed identically each rep (idempotent stores; x never written).
// Diagnostics: marginal warm-pass time = (kernel-30)/2 (x L3-resident after
// pass 1); FETCH under REP shows L3 absorption.
//
// Kernel structure is v7 verbatim (best: 114.9us): weights B2-B4 + biases in
// LDS fragment-image layout, B1 in regs, bf16 x staging, NBATCH=4, LB(256,2),
// 50.9KB LDS, T14 prefetch, wave-local fences A->B / C->D, lgkmcnt barriers.

typedef __bf16 bf16x8 __attribute__((ext_vector_type(8)));
typedef float  f32x4  __attribute__((ext_vector_type(4)));
typedef unsigned short u16;

#define REP 3
#define NBATCH 4
#define ITERS  NBATCH
#define HS  72   // sH row stride in u16 (144 B)
#define MBS 40   // sMB row stride in u16 (80 B)
#define XBS 40   // sXb row stride in u16 (80 B)

// u16 offsets into the single smem block (all 16B-aligned)
#define SH_OFF   0                     // 128*72  = 9216 u16
#define SMB_OFF  (SH_OFF + 128 * HS)   // 9216
#define SXB_OFF  (SMB_OFF + 128 * MBS) // 14336
#define FB2_OFF  (SXB_OFF + 64 * XBS)  // 16896 : 4 frags * 512 u16
#define FB3_OFF  (FB2_OFF + 4 * 512)   // 18944 : 8 frags
#define FB4_OFF  (FB3_OFF + 8 * 512)   // 23040 : 4 frags
#define BIAS_OFF (FB4_OFF + 4 * 512)   // 25088 : 192 f32 = 384 u16
#define SMEM_U16 (BIAS_OFF + 384)      // 25472 u16 = 50944 B

__device__ __forceinline__ u16 f2b(float f) { return __builtin_bit_cast(u16, (__bf16)f); }
__device__ __forceinline__ f32x4 MFMA(bf16x8 a, bf16x8 b, f32x4 c) {
    return __builtin_amdgcn_mfma_f32_16x16x32_bf16(a, b, c, 0, 0, 0);
}
__device__ __forceinline__ bf16x8 pack8(float4 a, float4 b) {
    bf16x8 r = {(__bf16)a.x, (__bf16)a.y, (__bf16)a.z, (__bf16)a.w,
                (__bf16)b.x, (__bf16)b.y, (__bf16)b.z, (__bf16)b.w};
    return r;
}
__device__ __forceinline__ uint2 relu_pack4(f32x4 acc, f32x4 bias) {
    uint2 o;
    o.x = (unsigned)f2b(fmaxf(acc[0] + bias[0], 0.f)) |
          ((unsigned)f2b(fmaxf(acc[1] + bias[1], 0.f)) << 16);
    o.y = (unsigned)f2b(fmaxf(acc[2] + bias[2], 0.f)) |
          ((unsigned)f2b(fmaxf(acc[3] + bias[3], 0.f)) << 16);
    return o;
}
__device__ __forceinline__ void wave_lds_fence() {
    asm volatile("s_waitcnt lgkmcnt(0)" ::: "memory");
}
__device__ __forceinline__ void barrier_lds() {
    asm volatile("s_waitcnt lgkmcnt(0)" ::: "memory");
    __builtin_amdgcn_s_barrier();
    asm volatile("" ::: "memory");
}

__global__ __launch_bounds__(256, 2)
void agn_mfma(const float* __restrict__ x, const float* __restrict__ Wm1,
              const float* __restrict__ bm1, const float* __restrict__ Wm2,
              const float* __restrict__ bm2, const float* __restrict__ Wu1,
              const float* __restrict__ bu1, const float* __restrict__ Wu2,
              const float* __restrict__ bu2, const float* __restrict__ rw_p,
              float* __restrict__ out)
{
    __shared__ __align__(16) u16 smem[SMEM_U16];  // 50944 B -> 3 blocks/CU

    const int t = threadIdx.x;
    const int w = t >> 6;
    const int lane = t & 63;
    const int ln = lane & 15;
    const int q  = lane >> 4;

    float* biasL = (float*)&smem[BIAS_OFF];

    // ---------------- prologue: biases + cold frags -> LDS (all waves) -----
    if (t < 64)  { biasL[t] = bm1[t]; biasL[64 + t] = bu1[t]; }
    if (t < 32)  { biasL[128 + t] = bm2[t]; biasL[160 + t] = bu2[t]; }
    if (w == 0) {                       // B2 frags: f = ks*2 + ot
#pragma unroll
        for (int ks = 0; ks < 2; ++ks)
#pragma unroll
            for (int ot = 0; ot < 2; ++ot) {
                bf16x8 v;
#pragma unroll
                for (int j = 0; j < 8; ++j)
                    v[j] = (__bf16)Wm2[(ks * 32 + q * 8 + j) * 32 + ot * 16 + ln];
                *(uint4*)&smem[FB2_OFF + (ks * 2 + ot) * 512 + lane * 8] =
                    __builtin_bit_cast(uint4, v);
            }
    } else if (w == 1 || w == 2) {      // B3 frags: f = ks*4 + ht, ks = w-1
        const int ks = w - 1;
#pragma unroll
        for (int ht = 0; ht < 4; ++ht) {
            bf16x8 v;
#pragma unroll
            for (int j = 0; j < 8; ++j)
                v[j] = (__bf16)Wu1[(ks * 32 + q * 8 + j) * 64 + ht * 16 + ln];
            *(uint4*)&smem[FB3_OFF + (ks * 4 + ht) * 512 + lane * 8] =
                __builtin_bit_cast(uint4, v);
        }
    } else {                            // B4 frags: f = ks*2 + s
#pragma unroll
        for (int ks = 0; ks < 2; ++ks)
#pragma unroll
            for (int s = 0; s < 2; ++s) {
                bf16x8 v;
#pragma unroll
                for (int j = 0; j < 8; ++j)
                    v[j] = (__bf16)Wu2[(ks * 32 + q * 8 + j) * 32 + s * 16 + ln];
                *(uint4*)&smem[FB4_OFF + (ks * 2 + s) * 512 + lane * 8] =
                    __builtin_bit_cast(uint4, v);
            }
    }

    // Hot B1 fragments in registers (used 2x per A-phase MFMA).
    bf16x8 B1a[4], B1b[4];
#pragma unroll
    for (int nt = 0; nt < 4; ++nt)
#pragma unroll
        for (int j = 0; j < 8; ++j) {
            B1a[nt][j] = (__bf16)Wm1[(q * 8 + j) * 64 + nt * 16 + ln];
            B1b[nt][j] = (__bf16)Wm1[(32 + q * 8 + j) * 64 + nt * 16 + ln];
        }

    const float rw = rw_p[0];
    const float om = 1.f - rw;
    const size_t base = (size_t)blockIdx.x * (NBATCH * 64 * 32);

    for (int rep = 0; rep < REP; ++rep) {

    // T14: first batch's x slice into registers (32B/thread, coalesced).
    float4 p0, p1;
    {
        const float* xp = x + base + t * 8;
        p0 = *(const float4*)xp;
        p1 = *(const float4*)(xp + 4);
    }

    for (int it = 0; it < ITERS; ++it) {
        const float* xit = x + base + (size_t)it * (64 * 32);
        float*       oit = out + base + (size_t)it * (64 * 32);

        // ===== Stage: regs -> sXb bf16 (row = t>>2, chunk = t&3) =====
        *(uint4*)&smem[SXB_OFF + (t >> 2) * XBS + (t & 3) * 8] =
            __builtin_bit_cast(uint4, pack8(p0, p1));
        barrier_lds();  // sXb ready (also covers prologue on iter 0)

        // T14: issue NEXT batch's x loads now; latency hides under A-D.
        if (it + 1 < ITERS) {
            const float* xn = xit + 64 * 32 + t * 8;
            p0 = *(const float4*)xn;
            p1 = *(const float4*)(xn + 4);
        }

        // ===== Phase A (swapped): h^T = Wm1t^T@xd^T + Wm1b^T@xs^T, relu =====
#pragma unroll
        for (int m = 0; m < 2; ++m) {
            const int erow = (2 * w + m) * 16 + ln;   // 0..127
            int e = erow;
            if (e >= 126) e = 0;  // pad rows, never read downstream
            const int dst  = (e < 63) ? e : e - 62;
            const int srcn = (e < 63) ? e + 1 : e - 63;
            bf16x8 Ad = __builtin_bit_cast(bf16x8, *(const uint4*)&smem[SXB_OFF + dst * XBS + q * 8]);
            bf16x8 As = __builtin_bit_cast(bf16x8, *(const uint4*)&smem[SXB_OFF + srcn * XBS + q * 8]);
            u16* rowp = &smem[SH_OFF + erow * HS];
#pragma unroll
            for (int ht = 0; ht < 4; ++ht) {
                f32x4 bias = *(const f32x4*)&biasL[ht * 16 + q * 4];
                f32x4 acc = {0.f, 0.f, 0.f, 0.f};
                acc = MFMA(B1a[ht], Ad, acc);
                acc = MFMA(B1b[ht], As, acc);
                *(uint2*)&rowp[ht * 16 + q * 4] = relu_pack4(acc, bias);
            }
        }
        wave_lds_fence();  // A->B wave-local (rows [32w,32w+32))

        // ===== Phase B (swapped): msgb^T = Wm2^T @ h^T, relu =====
        {
            bf16x8 W2[2][2];
            f32x4 bb[2];
#pragma unroll
            for (int s = 0; s < 2; ++s) {
                W2[0][s] = __builtin_bit_cast(bf16x8, *(const uint4*)&smem[FB2_OFF + (0 * 2 + s) * 512 + lane * 8]);
                W2[1][s] = __builtin_bit_cast(bf16x8, *(const uint4*)&smem[FB2_OFF + (1 * 2 + s) * 512 + lane * 8]);
                bb[s] = *(const f32x4*)&biasL[128 + s * 16 + q * 4];
            }
#pragma unroll
            for (int m = 0; m < 2; ++m) {
                const int row = (2 * w + m) * 16 + ln;
                bf16x8 A0 = __builtin_bit_cast(bf16x8, *(const uint4*)&smem[SH_OFF + row * HS + q * 8]);
                bf16x8 A1 = __builtin_bit_cast(bf16x8, *(const uint4*)&smem[SH_OFF + row * HS + 32 + q * 8]);
#pragma unroll
                for (int s = 0; s < 2; ++s) {
                    f32x4 acc = {0.f, 0.f, 0.f, 0.f};
                    acc = MFMA(W2[0][s], A0, acc);
                    acc = MFMA(W2[1][s], A1, acc);
                    *(uint2*)&smem[SMB_OFF + row * MBS + s * 16 + q * 4] = relu_pack4(acc, bb[s]);
                }
            }
        }
        barrier_lds();  // sMB scatter in C is cross-wave

        // Early residual loads for phase D (L2/L3-warm; hides under C).
        const int drow = w * 16 + ln;   // node 0..63 (same row C uses)
        float4 xv0 = *(const float4*)(xit + drow * 32 + 0 * 16 + q * 4);
        float4 xv1 = *(const float4*)(xit + drow * 32 + 1 * 16 + q * 4);

        // ===== Phase C (swapped): hu^T = Wu1^T @ [x | scatter(msgb)]^T, relu =====
        {
            const int row = drow;
            bf16x8 A0 = __builtin_bit_cast(bf16x8, *(const uint4*)&smem[SXB_OFF + row * XBS + q * 8]);
            float mv[8] = {0.f, 0.f, 0.f, 0.f, 0.f, 0.f, 0.f, 0.f};
            if (row < 63) {
                uint4 u = *(const uint4*)&smem[SMB_OFF + row * MBS + q * 8];
                const unsigned* pu = (const unsigned*)&u;
#pragma unroll
                for (int h = 0; h < 4; ++h) {
                    mv[2 * h]     += __uint_as_float(pu[h] << 16);
                    mv[2 * h + 1] += __uint_as_float(pu[h] & 0xFFFF0000u);
                }
            }
            if (row > 0) {
                uint4 u = *(const uint4*)&smem[SMB_OFF + (62 + row) * MBS + q * 8];
                const unsigned* pu = (const unsigned*)&u;
#pragma unroll
                for (int h = 0; h < 4; ++h) {
                    mv[2 * h]     += __uint_as_float(pu[h] << 16);
                    mv[2 * h + 1] += __uint_as_float(pu[h] & 0xFFFF0000u);
                }
            }
            bf16x8 A1;
#pragma unroll
            for (int j = 0; j < 8; ++j) A1[j] = (__bf16)mv[j];
#pragma unroll
            for (int ht = 0; ht < 4; ++ht) {
                bf16x8 W0 = __builtin_bit_cast(bf16x8, *(const uint4*)&smem[FB3_OFF + (0 * 4 + ht) * 512 + lane * 8]);
                bf16x8 W1 = __builtin_bit_cast(bf16x8, *(const uint4*)&smem[FB3_OFF + (1 * 4 + ht) * 512 + lane * 8]);
                f32x4 bias = *(const f32x4*)&biasL[64 + ht * 16 + q * 4];
                f32x4 acc = {0.f, 0.f, 0.f, 0.f};
                acc = MFMA(W0, A0, acc);
                acc = MFMA(W1, A1, acc);
                *(uint2*)&smem[SH_OFF + row * HS + ht * 16 + q * 4] = relu_pack4(acc, bias);
            }
        }
        wave_lds_fence();  // C->D wave-local (rows [16w,16w+16))

        // ===== Phase D (swapped): out^T = Wu2^T @ hu^T; full-line stores =====
        {
            const int row = drow;
            bf16x8 A0 = __builtin_bit_cast(bf16x8, *(const uint4*)&smem[SH_OFF + row * HS + q * 8]);
            bf16x8 A1 = __builtin_bit_cast(bf16x8, *(const uint4*)&smem[SH_OFF + row * HS + 32 + q * 8]);
#pragma unroll
            for (int s = 0; s < 2; ++s) {
                bf16x8 W0 = __builtin_bit_cast(bf16x8, *(const uint4*)&smem[FB4_OFF + (0 * 2 + s) * 512 + lane * 8]);
                bf16x8 W1 = __builtin_bit_cast(bf16x8, *(const uint4*)&smem[FB4_OFF + (1 * 2 + s) * 512 + lane * 8]);
                f32x4 bias = *(const f32x4*)&biasL[160 + s * 16 + q * 4];
                f32x4 acc = {0.f, 0.f, 0.f, 0.f};
                acc = MFMA(W0, A0, acc);
                acc = MFMA(W1, A1, acc);
                const float4 xv = s ? xv1 : xv0;
                float4 o;
                o.x = rw * (acc[0] + bias[0]) + om * xv.x;
                o.y = rw * (acc[1] + bias[1]) + om * xv.y;
                o.z = rw * (acc[2] + bias[2]) + om * xv.z;
                o.w = rw * (acc[3] + bias[3]) + om * xv.w;
                *(float4*)(oit + row * 32 + s * 16 + q * 4) = o;
            }
        }
        barrier_lds();  // sH/sMB/sXb consumed before next iter overwrites
    }
    }  // rep
}

extern "C" void kernel_launch(void* const* d_in, const int* in_sizes, int n_in,
                              void* d_out, int out_size, void* d_ws, size_t ws_size,
                              hipStream_t stream) {
    const float* x   = (const float*)d_in[0];
    const float* Wm1 = (const float*)d_in[1];
    const float* bm1 = (const float*)d_in[2];
    const float* Wm2 = (const float*)d_in[3];
    const float* bm2 = (const float*)d_in[4];
    const float* Wu1 = (const float*)d_in[5];
    const float* bu1 = (const float*)d_in[6];
    const float* Wu2 = (const float*)d_in[7];
    const float* bu2 = (const float*)d_in[8];
    const float* rw  = (const float*)d_in[9];
    float* out = (float*)d_out;

    const int B = in_sizes[0] / (64 * 32);
    agn_mfma<<<B / NBATCH, 256, 0, stream>>>(x, Wm1, bm1, Wm2, bm2, Wu1, bu1, Wu2, bu2, rw, out);
}

// Round 11
// 108.495 us; speedup vs baseline: 1.3592x; 1.3592x over previous
//
#include <hip/hip_runtime.h>
#include <hip/hip_bf16.h>

// AdaptiveGraphNetwork via MFMA 16x16x32 bf16. B=4096, N=64, D=32, H=64.
//
// v10: FULLY INDEPENDENT WAVES. v9's REP-instrumented counters: MfmaUtil 16.7,
// VALUBusy 38.7, HBM 22%, occupancy 23%, nothing saturated -> latency-bound on
// the block-wide-sync'd 4-phase chain. v10 removes ALL main-loop barriers:
//  * dst-owned edges (v8-verified algebra+masks): wave w owns 32 nodes of
//    batch (it*2 + (w>>1)); computes h_fwd/h_bwd itself; scatter = in-register
//    masked add. Zero cross-wave data flow.
//  * per-wave LDS regions: sXw (34 rows: nodes g0-1..g0+32, clamped dup
//    boundary rows -- reads masked), sHw (64 h rows), sMw (32 msg rows).
//    Phase boundaries = wave-local lgkmcnt fences only.
//  * NBATCH=8 -> grid 512 = 2 blocks/CU uniform (no dispatch tail).
//  * 2 blocks/CU -> 256-VGPR budget: ALL weight frags hoisted to registers
//    (B1 32 + W2/W3/W4 64 VGPR) after a 2-barrier prologue LDS stage.
//  * bias in MFMA C-operand (saves the f32 bias adds); phase A factors the
//    shared B1a@Xd: t=bias+B1a@Xd; af=MFMA(B1b,Xn,t); ab=MFMA(B1b,Xp,t)
//    (3 MFMA not 4); Xd kept in regs A->C; T14 stage prefetch; early
//    residual loads.
//
// Fragment maps (m89/m91-verified): A[m=lane&15][k=quad*8+j],
// B[k=quad*8+j][n=lane&15], C/D[row=quad*4+reg][col=lane&15].
// A-frag of W^T == B-frag of W: one fragment image serves both orientations.

typedef __bf16 bf16x8 __attribute__((ext_vector_type(8)));
typedef float  f32x4  __attribute__((ext_vector_type(4)));
typedef unsigned short u16;

#define NBATCH 8              // per WG; 2 batches/iter (waves 01 / 23)
#define ITERS (NBATCH / 2)
#define HS 72                 // sHw row stride in u16 (144 B)
#define MS 40                 // sMw row stride in u16 (80 B)
#define XS 40                 // sXw row stride in u16 (80 B)

// u16 offsets (all 16B-aligned)
#define SHW(w)  ((w) * (64 * HS))               // 4 x 4608
#define SMW(w)  (4 * 64 * HS + (w) * (32 * MS)) // 18432 + w*1280
#define SXW(w)  (23552 + (w) * (34 * XS))       // 23552 + w*1360 -> 28992
#define FB2_OFF  28992                          // 4 frags * 512 u16
#define FB3_OFF  (FB2_OFF + 4 * 512)            // 8 frags
#define FB4_OFF  (FB3_OFF + 8 * 512)            // 4 frags
#define BIAS_OFF (FB4_OFF + 4 * 512)            // 192 f32 = 384 u16
#define SMEM_U16 (BIAS_OFF + 384)               // 37568 u16 = 75136 B -> 2/CU

__device__ __forceinline__ u16 f2b(float f) { return __builtin_bit_cast(u16, (__bf16)f); }
__device__ __forceinline__ f32x4 MFMA(bf16x8 a, bf16x8 b, f32x4 c) {
    return __builtin_amdgcn_mfma_f32_16x16x32_bf16(a, b, c, 0, 0, 0);
}
__device__ __forceinline__ bf16x8 pack8(float4 a, float4 b) {
    bf16x8 r = {(__bf16)a.x, (__bf16)a.y, (__bf16)a.z, (__bf16)a.w,
                (__bf16)b.x, (__bf16)b.y, (__bf16)b.z, (__bf16)b.w};
    return r;
}
// relu + pack (bias already inside acc via C-operand init)
__device__ __forceinline__ uint2 relu_pack4_nb(f32x4 acc) {
    uint2 o;
    o.x = (unsigned)f2b(fmaxf(acc[0], 0.f)) | ((unsigned)f2b(fmaxf(acc[1], 0.f)) << 16);
    o.y = (unsigned)f2b(fmaxf(acc[2], 0.f)) | ((unsigned)f2b(fmaxf(acc[3], 0.f)) << 16);
    return o;
}
__device__ __forceinline__ void wave_lds_fence() {
    asm volatile("s_waitcnt lgkmcnt(0)" ::: "memory");
}
__device__ __forceinline__ void barrier_lds() {
    asm volatile("s_waitcnt lgkmcnt(0)" ::: "memory");
    __builtin_amdgcn_s_barrier();
    asm volatile("" ::: "memory");
}

__global__ __launch_bounds__(256, 2)
void agn_mfma(const float* __restrict__ x, const float* __restrict__ Wm1,
              const float* __restrict__ bm1, const float* __restrict__ Wm2,
              const float* __restrict__ bm2, const float* __restrict__ Wu1,
              const float* __restrict__ bu1, const float* __restrict__ Wu2,
              const float* __restrict__ bu2, const float* __restrict__ rw_p,
              float* __restrict__ out)
{
    __shared__ __align__(16) u16 smem[SMEM_U16];

    const int t = threadIdx.x;
    const int w = t >> 6;
    const int lane = t & 63;
    const int ln = lane & 15;
    const int q  = lane >> 4;
    const int g0 = (w & 1) * 32;           // node-half base within the batch
    const int shw = SHW(w), smw = SMW(w), sxw = SXW(w);

    float* biasL = (float*)&smem[BIAS_OFF];  // [0..63]=bm1, [64..127]=bu1,
                                             // [128..159]=bm2, [160..191]=bu2

    // ---------- prologue: biases + frag images -> LDS (split across waves) --
    if (t < 64)  { biasL[t] = bm1[t]; biasL[64 + t] = bu1[t]; }
    if (t < 32)  { biasL[128 + t] = bm2[t]; biasL[160 + t] = bu2[t]; }
    if (w == 0) {                       // B2 frags: f = ks*2 + s
#pragma unroll
        for (int ks = 0; ks < 2; ++ks)
#pragma unroll
            for (int s = 0; s < 2; ++s) {
                bf16x8 v;
#pragma unroll
                for (int j = 0; j < 8; ++j)
                    v[j] = (__bf16)Wm2[(ks * 32 + q * 8 + j) * 32 + s * 16 + ln];
                *(uint4*)&smem[FB2_OFF + (ks * 2 + s) * 512 + lane * 8] =
                    __builtin_bit_cast(uint4, v);
            }
    } else if (w == 1 || w == 2) {      // B3 frags: f = ks*4 + ht, ks = w-1
        const int ks = w - 1;
#pragma unroll
        for (int ht = 0; ht < 4; ++ht) {
            bf16x8 v;
#pragma unroll
            for (int j = 0; j < 8; ++j)
                v[j] = (__bf16)Wu1[(ks * 32 + q * 8 + j) * 64 + ht * 16 + ln];
            *(uint4*)&smem[FB3_OFF + (ks * 4 + ht) * 512 + lane * 8] =
                __builtin_bit_cast(uint4, v);
        }
    } else {                            // B4 frags: f = ks*2 + s
#pragma unroll
        for (int ks = 0; ks < 2; ++ks)
#pragma unroll
            for (int s = 0; s < 2; ++s) {
                bf16x8 v;
#pragma unroll
                for (int j = 0; j < 8; ++j)
                    v[j] = (__bf16)Wu2[(ks * 32 + q * 8 + j) * 32 + s * 16 + ln];
                *(uint4*)&smem[FB4_OFF + (ks * 2 + s) * 512 + lane * 8] =
                    __builtin_bit_cast(uint4, v);
            }
    }

    // Hot B1 fragments from global.
    bf16x8 B1a[4], B1b[4];
#pragma unroll
    for (int nt = 0; nt < 4; ++nt)
#pragma unroll
        for (int j = 0; j < 8; ++j) {
            B1a[nt][j] = (__bf16)Wm1[(q * 8 + j) * 64 + nt * 16 + ln];
            B1b[nt][j] = (__bf16)Wm1[(32 + q * 8 + j) * 64 + nt * 16 + ln];
        }

    barrier_lds();  // frag images complete

    // Hoist W2/W3/W4 fragment images into registers (64 VGPR).
    bf16x8 W2[2][2], W3[2][4], W4[2][2];
#pragma unroll
    for (int ks = 0; ks < 2; ++ks) {
#pragma unroll
        for (int s = 0; s < 2; ++s) {
            W2[ks][s] = __builtin_bit_cast(bf16x8, *(const uint4*)&smem[FB2_OFF + (ks * 2 + s) * 512 + lane * 8]);
            W4[ks][s] = __builtin_bit_cast(bf16x8, *(const uint4*)&smem[FB4_OFF + (ks * 2 + s) * 512 + lane * 8]);
        }
#pragma unroll
        for (int ht = 0; ht < 4; ++ht)
            W3[ks][ht] = __builtin_bit_cast(bf16x8, *(const uint4*)&smem[FB3_OFF + (ks * 4 + ht) * 512 + lane * 8]);
    }
    barrier_lds();  // LAST barrier in the kernel.

    const float rw = rw_p[0];
    const float om = 1.f - rw;
    const size_t base = (size_t)blockIdx.x * (NBATCH * 64 * 32);

    // Stage-assignment precompute: 34 rows x 4 chunks(8 f32) = 136 slots.
    int goff[3], loff[3];
#pragma unroll
    for (int rnd = 0; rnd < 3; ++rnd) {
        const int k = lane + 64 * rnd;       // rnd 2 valid only for lane<8
        const int r = (k >> 2), ch = (k & 3);
        int gn = g0 - 1 + r;
        gn = gn < 0 ? 0 : (gn > 63 ? 63 : gn);   // clamped dups -> masked reads
        goff[rnd] = gn * 32 + ch * 8;            // f32 units
        loff[rnd] = sxw + r * XS + ch * 8;       // u16 units
    }

    // T14 prefetch: first batch's slots into regs.
    float4 pa[3], pb[3];
    {
        const float* xb0 = x + base + (size_t)(w >> 1) * (64 * 32);
        pa[0] = *(const float4*)(xb0 + goff[0]); pb[0] = *(const float4*)(xb0 + goff[0] + 4);
        pa[1] = *(const float4*)(xb0 + goff[1]); pb[1] = *(const float4*)(xb0 + goff[1] + 4);
        if (lane < 8) { pa[2] = *(const float4*)(xb0 + goff[2]); pb[2] = *(const float4*)(xb0 + goff[2] + 4); }
    }

    for (int it = 0; it < ITERS; ++it) {
        const float* xb = x + base + (size_t)(it * 2 + (w >> 1)) * (64 * 32);
        float*       ob = out + base + (size_t)(it * 2 + (w >> 1)) * (64 * 32);

        // ===== Stage: prefetch regs -> sXw (wave-private) =====
        *(uint4*)&smem[loff[0]] = __builtin_bit_cast(uint4, pack8(pa[0], pb[0]));
        *(uint4*)&smem[loff[1]] = __builtin_bit_cast(uint4, pack8(pa[1], pb[1]));
        if (lane < 8)
            *(uint4*)&smem[loff[2]] = __builtin_bit_cast(uint4, pack8(pa[2], pb[2]));
        wave_lds_fence();

        // T14: issue NEXT iteration's loads (hide under phases A-D).
        if (it + 1 < ITERS) {
            const float* xn = xb + 2 * (64 * 32);
            pa[0] = *(const float4*)(xn + goff[0]); pb[0] = *(const float4*)(xn + goff[0] + 4);
            pa[1] = *(const float4*)(xn + goff[1]); pb[1] = *(const float4*)(xn + goff[1] + 4);
            if (lane < 8) { pa[2] = *(const float4*)(xn + goff[2]); pb[2] = *(const float4*)(xn + goff[2] + 4); }
        }

        bf16x8 Xd[2];  // dst-node x frags, reused in phase C

        // ===== Phase A: h_fwd/h_bwd for this wave's 32 nodes =====
#pragma unroll
        for (int nt = 0; nt < 2; ++nt) {
            const int nl = nt * 16 + ln;          // node-local 0..31
            const int r = nl + 1;                 // sXw row (row0 = g0-1)
            Xd[nt]    = __builtin_bit_cast(bf16x8, *(const uint4*)&smem[sxw + r * XS + q * 8]);
            bf16x8 Xn = __builtin_bit_cast(bf16x8, *(const uint4*)&smem[sxw + (r + 1) * XS + q * 8]);
            bf16x8 Xp = __builtin_bit_cast(bf16x8, *(const uint4*)&smem[sxw + (r - 1) * XS + q * 8]);
            u16* rf = &smem[shw + nl * HS];
            u16* rb = &smem[shw + (32 + nl) * HS];
#pragma unroll
            for (int ht = 0; ht < 4; ++ht) {
                f32x4 tt = *(const f32x4*)&biasL[ht * 16 + q * 4];  // bias in C-op
                tt = MFMA(B1a[ht], Xd[nt], tt);                     // shared term
                f32x4 af = MFMA(B1b[ht], Xn, tt);
                f32x4 ab = MFMA(B1b[ht], Xp, tt);
                *(uint2*)&rf[ht * 16 + q * 4] = relu_pack4_nb(af);
                *(uint2*)&rb[ht * 16 + q * 4] = relu_pack4_nb(ab);
            }
        }
        wave_lds_fence();

        // ===== Phase B: msgs + in-register masked scatter -> sMw =====
#pragma unroll
        for (int nt = 0; nt < 2; ++nt) {
            const int nl = nt * 16 + ln;
            const int n = g0 + nl;
            bf16x8 hf0 = __builtin_bit_cast(bf16x8, *(const uint4*)&smem[shw + nl * HS + q * 8]);
            bf16x8 hf1 = __builtin_bit_cast(bf16x8, *(const uint4*)&smem[shw + nl * HS + 32 + q * 8]);
            bf16x8 hb0 = __builtin_bit_cast(bf16x8, *(const uint4*)&smem[shw + (32 + nl) * HS + q * 8]);
            bf16x8 hb1 = __builtin_bit_cast(bf16x8, *(const uint4*)&smem[shw + (32 + nl) * HS + 32 + q * 8]);
#pragma unroll
            for (int s = 0; s < 2; ++s) {
                f32x4 bb = *(const f32x4*)&biasL[128 + s * 16 + q * 4];
                f32x4 cf = MFMA(W2[0][s], hf0, bb); cf = MFMA(W2[1][s], hf1, cf);
                f32x4 cb = MFMA(W2[0][s], hb0, bb); cb = MFMA(W2[1][s], hb1, cb);
                float m4[4];
#pragma unroll
                for (int r = 0; r < 4; ++r) {
                    float vf = (n != 63) ? fmaxf(cf[r], 0.f) : 0.f;
                    float vb = (n != 0)  ? fmaxf(cb[r], 0.f) : 0.f;
                    m4[r] = vf + vb;
                }
                uint2 o;
                o.x = (unsigned)f2b(m4[0]) | ((unsigned)f2b(m4[1]) << 16);
                o.y = (unsigned)f2b(m4[2]) | ((unsigned)f2b(m4[3]) << 16);
                *(uint2*)&smem[smw + nl * MS + s * 16 + q * 4] = o;
            }
        }

        // Early residual loads (global f32; hide under C's LDS/MFMA work).
        float4 xvp[2][2];
#pragma unroll
        for (int nt = 0; nt < 2; ++nt)
#pragma unroll
            for (int s = 0; s < 2; ++s)
                xvp[nt][s] = *(const float4*)(xb + (g0 + nt * 16 + ln) * 32 + s * 16 + q * 4);

        wave_lds_fence();

        // ===== Phase C: hu^T = Wu1^T @ [x | m]^T, relu -> sHw fwd rows =====
#pragma unroll
        for (int nt = 0; nt < 2; ++nt) {
            const int nl = nt * 16 + ln;
            bf16x8 A1 = __builtin_bit_cast(bf16x8, *(const uint4*)&smem[smw + nl * MS + q * 8]);
#pragma unroll
            for (int ht = 0; ht < 4; ++ht) {
                f32x4 tt = *(const f32x4*)&biasL[64 + ht * 16 + q * 4];
                tt = MFMA(W3[0][ht], Xd[nt], tt);
                tt = MFMA(W3[1][ht], A1, tt);
                *(uint2*)&smem[shw + nl * HS + ht * 16 + q * 4] = relu_pack4_nb(tt);
            }
        }
        wave_lds_fence();

        // ===== Phase D: out^T = Wu2^T @ hu^T; residual; full-line stores =====
#pragma unroll
        for (int nt = 0; nt < 2; ++nt) {
            const int nl = nt * 16 + ln;
            const int n = g0 + nl;
            bf16x8 A0 = __builtin_bit_cast(bf16x8, *(const uint4*)&smem[shw + nl * HS + q * 8]);
            bf16x8 A1 = __builtin_bit_cast(bf16x8, *(const uint4*)&smem[shw + nl * HS + 32 + q * 8]);
#pragma unroll
            for (int s = 0; s < 2; ++s) {
                f32x4 tt = *(const f32x4*)&biasL[160 + s * 16 + q * 4];
                tt = MFMA(W4[0][s], A0, tt);
                tt = MFMA(W4[1][s], A1, tt);
                const float4 xv = xvp[nt][s];
                float4 o;
                o.x = rw * tt[0] + om * xv.x;
                o.y = rw * tt[1] + om * xv.y;
                o.z = rw * tt[2] + om * xv.z;
                o.w = rw * tt[3] + om * xv.w;
                *(float4*)(ob + n * 32 + s * 16 + q * 4) = o;
            }
        }
        wave_lds_fence();  // drain before next iter overwrites this wave's rows
    }
}

extern "C" void kernel_launch(void* const* d_in, const int* in_sizes, int n_in,
                              void* d_out, int out_size, void* d_ws, size_t ws_size,
                              hipStream_t stream) {
    const float* x   = (const float*)d_in[0];
    const float* Wm1 = (const float*)d_in[1];
    const float* bm1 = (const float*)d_in[2];
    const float* Wm2 = (const float*)d_in[3];
    const float* bm2 = (const float*)d_in[4];
    const float* Wu1 = (const float*)d_in[5];
    const float* bu1 = (const float*)d_in[6];
    const float* Wu2 = (const float*)d_in[7];
    const float* bu2 = (const float*)d_in[8];
    const float* rw  = (const float*)d_in[9];
    float* out = (float*)d_out;

    const int B = in_sizes[0] / (64 * 32);
    agn_mfma<<<B / NBATCH, 256, 0, stream>>>(x, Wm1, bm1, Wm2, bm2, Wu1, bu1, Wu2, bu2, rw, out);
}